// Round 5
// baseline (1057.921 us; speedup 1.0000x reference)
//
#include <hip/hip_runtime.h>
#include <hip/hip_bf16.h>

// VSSBlock: B=2 H=64 W=64 C=192 DM=384 N=16 R=12 K=4 L=4096
// R5: single-pass selective scan with decoupled lookback (ticket-ordered, device-scope
//     flags). Segment transform is affine h -> D h + E with D[n]=exp(a_n * cumDelta),
//     so aggregates are (scalar cumDelta, E[16]) per thread. Phase A keeps cumD_t and
//     y0_t in registers; phase C applies the h_in correction and atomicAdds into ysum.
//     Sigmoid identity exp(-softplus(x)) = 1/(1+e^x) removes one transcendental/step.
//     MFMA GEMMs + producers unchanged from R4.

typedef __attribute__((ext_vector_type(8))) short short8;     // 8 bf16 = 4 VGPRs
typedef __attribute__((ext_vector_type(4))) float floatx4;    // fp32 accum frag

// ---------------- LayerNorm (pre-norm, eps 1e-6), C=192 -> bf16 ----------------
__global__ __launch_bounds__(256) void k_ln(const float* __restrict__ in,
                                            const float* __restrict__ g,
                                            const float* __restrict__ be,
                                            __hip_bfloat16* __restrict__ out) {
  int row = blockIdx.x * 4 + (threadIdx.x >> 6);
  int lane = threadIdx.x & 63;
  const float* x = in + (long)row * 192;
  float v0 = x[lane], v1 = x[lane + 64], v2 = x[lane + 128];
  float s = v0 + v1 + v2;
  float s2 = v0 * v0 + v1 * v1 + v2 * v2;
  #pragma unroll
  for (int o = 32; o > 0; o >>= 1) { s += __shfl_xor(s, o); s2 += __shfl_xor(s2, o); }
  float mu = s * (1.f / 192.f);
  float var = s2 * (1.f / 192.f) - mu * mu;
  float r = rsqrtf(var + 1e-6f);
  __hip_bfloat16* op = out + (long)row * 192;
  op[lane]       = __float2bfloat16((v0 - mu) * r * g[lane]       + be[lane]);
  op[lane + 64]  = __float2bfloat16((v1 - mu) * r * g[lane + 64]  + be[lane + 64]);
  op[lane + 128] = __float2bfloat16((v2 - mu) * r * g[lane + 128] + be[lane + 128]);
}

// ---------------- pack weights -> bf16, transposed to (N x K) ----------------
__global__ __launch_bounds__(256) void k_packw(const float* __restrict__ ipw,
                                               const float* __restrict__ xpw,
                                               const float* __restrict__ opw,
                                               __hip_bfloat16* __restrict__ Wt1,
                                               __hip_bfloat16* __restrict__ Wt2,
                                               __hip_bfloat16* __restrict__ Wt3) {
  int idx = blockIdx.x * 256 + threadIdx.x;
  if (idx < 147456) {                       // Wt1[n][k] = ipw[k][n]
    int n = idx / 192, k = idx - n * 192;
    Wt1[idx] = __float2bfloat16(ipw[(long)k * 768 + n]);
  } else if (idx < 147456 + 73728) {        // Wt2[j][d]
    int t = idx - 147456;
    int j = t / 384;
    float v = (j < 176) ? xpw[t] : 0.f;
    Wt2[t] = __float2bfloat16(v);
  } else if (idx < 147456 + 73728 + 73728) {// Wt3[n][k] = opw[k][n]
    int t = idx - 147456 - 73728;
    int n = t / 384, k = t - n * 384;
    Wt3[t] = __float2bfloat16(opw[(long)k * 192 + n]);
  }
}

// ---------------- bf16 MFMA GEMM: Co(MxN) = A(MxK) * Bt(NxK)^T [+ Res] ----------------
template <int RES>
__global__ __launch_bounds__(256) void k_gemm_mfma(const __hip_bfloat16* __restrict__ A,
                                                   const __hip_bfloat16* __restrict__ Bt,
                                                   const float* __restrict__ Res,
                                                   float* __restrict__ Co,
                                                   int M, int N, int Kk) {
  __shared__ __align__(16) short As[128 * 32];
  __shared__ __align__(16) short Bs[64 * 32];
  int tid = threadIdx.x;
  int wave = tid >> 6, lane = tid & 63;
  int mlane = lane & 15, quad = lane >> 4;
  int row0 = blockIdx.y * 128, col0 = blockIdx.x * 64;
  int wr = wave & 1, wc = wave >> 1;
  floatx4 acc[4][2];
  #pragma unroll
  for (int mi = 0; mi < 4; mi++)
    #pragma unroll
    for (int ni = 0; ni < 2; ni++) acc[mi][ni] = (floatx4){0.f, 0.f, 0.f, 0.f};

  for (int k0 = 0; k0 < Kk; k0 += 32) {
    #pragma unroll
    for (int c = tid; c < 512; c += 256) {
      int r = c >> 2, off = (c & 3) * 8;
      *(float4*)&As[r * 32 + off] = *(const float4*)&A[(long)(row0 + r) * Kk + k0 + off];
    }
    {
      int c = tid;
      int r = c >> 2, off = (c & 3) * 8;
      *(float4*)&Bs[r * 32 + off] = *(const float4*)&Bt[(long)(col0 + r) * Kk + k0 + off];
    }
    __syncthreads();
    short8 af[4], bf[2];
    #pragma unroll
    for (int mi = 0; mi < 4; mi++)
      af[mi] = *(const short8*)&As[(wr * 64 + mi * 16 + mlane) * 32 + quad * 8];
    #pragma unroll
    for (int ni = 0; ni < 2; ni++)
      bf[ni] = *(const short8*)&Bs[(wc * 32 + ni * 16 + mlane) * 32 + quad * 8];
    #pragma unroll
    for (int mi = 0; mi < 4; mi++)
      #pragma unroll
      for (int ni = 0; ni < 2; ni++)
        acc[mi][ni] = __builtin_amdgcn_mfma_f32_16x16x32_bf16(af[mi], bf[ni], acc[mi][ni], 0, 0, 0);
    __syncthreads();
  }
  #pragma unroll
  for (int mi = 0; mi < 4; mi++) {
    #pragma unroll
    for (int ni = 0; ni < 2; ni++) {
      int cc = col0 + wc * 32 + ni * 16 + mlane;
      #pragma unroll
      for (int i = 0; i < 4; i++) {
        int rr = row0 + wr * 64 + mi * 16 + quad * 4 + i;
        float v = acc[mi][ni][i];
        if (RES) v += Res[(long)rr * N + cc];
        Co[(long)rr * N + cc] = v;
      }
    }
  }
}

// ---------------- depthwise 3x3 conv + bias + SiLU; writes fp32 xc + bf16 xcb ----------------
__global__ __launch_bounds__(384) void k_conv(const float* __restrict__ xz,
                                              const float* __restrict__ cw,
                                              const float* __restrict__ cb,
                                              float* __restrict__ xc,
                                              __hip_bfloat16* __restrict__ xcb) {
  int row = blockIdx.x;
  int b = row >> 12, p = row & 4095;
  int h = p >> 6, w0 = p & 63;
  int d = threadIdx.x;
  float acc = cb[d];
  const float* wt = cw + d * 9;
  #pragma unroll
  for (int dh = -1; dh <= 1; dh++) {
    int hh = h + dh;
    if (hh < 0 || hh > 63) continue;
    #pragma unroll
    for (int dw = -1; dw <= 1; dw++) {
      int ww = w0 + dw;
      if (ww < 0 || ww > 63) continue;
      acc += xz[((long)(b << 12) + (hh << 6) + ww) * 768 + d] * wt[(dh + 1) * 3 + (dw + 1)];
    }
  }
  float sg = 1.f / (1.f + __expf(-acc));
  float v = acc * sg;
  xc[(long)row * 384 + d] = v;
  xcb[(long)row * 384 + d] = __float2bfloat16(v);
}

// direction mapping: scan position l (direction k) -> pixel index p
__device__ __forceinline__ int dir_pix(int k, int l) {
  if (k == 0) return l;
  if (k == 1) return ((l & 63) << 6) | (l >> 6);
  if (k == 2) return 4095 - l;
  int l2 = 4095 - l;
  return ((l2 & 63) << 6) | (l2 >> 6);
}

// ---------------- repack pixel-major xdbl -> scan-ordered dts/Bs/Cs ----------------
__global__ __launch_bounds__(256) void k_repack(const float* __restrict__ xdbl,
                                                float* __restrict__ dtsS,
                                                float* __restrict__ BsS,
                                                float* __restrict__ CsS) {
  int bid = blockIdx.x;
  int lt = bid & 63, bk = bid >> 6;
  int k = bk & 3, b = bk >> 2;
  int l0 = lt * 64;
  long bpix = (long)(b << 12);
  int kc = k * 44;
  for (int i = threadIdx.x; i < 64 * 44; i += 256) {
    int t = i / 44, c = i - t * 44;
    int p = dir_pix(k, l0 + t);
    float v = xdbl[(bpix + p) * 192 + kc + c];
    long lbase = (long)bk * 4096 + l0 + t;
    if (c < 12)      dtsS[lbase * 12 + c] = v;
    else if (c < 28) BsS[lbase * 16 + (c - 12)] = v;
    else             CsS[lbase * 16 + (c - 28)] = v;
  }
}

// powers: pws[n] = r^(n+1), log-depth pairing
__device__ __forceinline__ void pow16(float r, float* pws) {
  pws[0] = r;
  #pragma unroll
  for (int n = 1; n < 16; n++) {
    int m = n + 1, c = (m + 1) / 2, f = m - c;
    pws[n] = pws[c - 1] * pws[f - 1];
  }
}

// ---------------- single-pass selective scan, decoupled lookback ----------------
// 1024 logical segments: chain = ticket&7 (=b*4+k), s = ticket>>3 (128 segs x 32 steps).
// Aggregate per (segment, d): scalar cumDelta + E[16]. flags: 0=none,1=aggregate,2=inclusive.
__global__ __launch_bounds__(384) void k_scan_one(
    const float* __restrict__ dtsS, const float* __restrict__ BsS,
    const float* __restrict__ CsS, const float* __restrict__ xc,
    const float* __restrict__ A_logs, const float* __restrict__ dt_w,
    const float* __restrict__ dt_b,
    float* __restrict__ Eb, float* __restrict__ INCb, float* __restrict__ Dend,
    int* __restrict__ flags, int* __restrict__ ticket,
    float* __restrict__ ysum) {
  __shared__ int sh_t, sh_f;
  int d = threadIdx.x;
  if (d == 0) sh_t = atomicAdd(ticket, 1) & 1023;  // mask: rocprof replay safety
  __syncthreads();
  int my = sh_t;
  int chain = my & 7, s = my >> 3;
  int k = chain & 3, b = chain >> 2;
  int g = chain * 128 + s;

  float w[12];
  const float* dwp = dt_w + ((long)(k * 384) + d) * 12;
  #pragma unroll
  for (int r = 0; r < 12; r++) w[r] = dwp[r];
  float db = dt_b[k * 384 + d];
  const float* al = A_logs + ((long)(k * 384) + d) * 16;
  bool pw = true;
  float av[16];
  #pragma unroll
  for (int n = 0; n < 16; n++) {
    float a = __expf(al[n]);
    av[n] = -a;
    pw = pw && (fabsf(a - (float)(n + 1)) < 1e-3f);
  }

  long lb = (long)chain * 4096 + s * 32;
  long bpix = (long)(b << 12);
  float h[16];
  #pragma unroll
  for (int n = 0; n < 16; n++) h[n] = 0.f;
  float cum = 0.f;
  float cumD[32], y0s[32];

  // ---- phase A: local scan (h_in = 0), keep cumD_t and y0_t in registers ----
  if (pw) {
    #pragma unroll
    for (int t = 0; t < 32; t++) {
      const float4* dq = (const float4*)(dtsS + (lb + t) * 12);
      float4 q0 = dq[0], q1 = dq[1], q2 = dq[2];
      float x = db + q0.x * w[0] + q0.y * w[1] + q0.z * w[2] + q0.w * w[3]
                   + q1.x * w[4] + q1.y * w[5] + q1.z * w[6] + q1.w * w[7]
                   + q2.x * w[8] + q2.y * w[9] + q2.z * w[10] + q2.w * w[11];
      float e = __expf(x);
      float delta = (x > 15.f) ? x : __logf(1.f + e);
      cum += delta; cumD[t] = cum;
      int p = dir_pix(k, s * 32 + t);
      float u = xc[(bpix + p) * 384 + d];
      float du = delta * u;
      float rr = __builtin_amdgcn_rcpf(1.f + e);  // exp(-softplus(x)) == sigmoid(-x)
      float pws[16]; pow16(rr, pws);
      const float4* Bq = (const float4*)(BsS + (lb + t) * 16);
      float4 b0 = Bq[0], b1 = Bq[1], b2 = Bq[2], b3 = Bq[3];
      float Bl[16] = {b0.x, b0.y, b0.z, b0.w, b1.x, b1.y, b1.z, b1.w,
                      b2.x, b2.y, b2.z, b2.w, b3.x, b3.y, b3.z, b3.w};
      const float4* Cq = (const float4*)(CsS + (lb + t) * 16);
      float4 c0 = Cq[0], c1 = Cq[1], c2 = Cq[2], c3 = Cq[3];
      float Cl[16] = {c0.x, c0.y, c0.z, c0.w, c1.x, c1.y, c1.z, c1.w,
                      c2.x, c2.y, c2.z, c2.w, c3.x, c3.y, c3.z, c3.w};
      float y = 0.f;
      #pragma unroll
      for (int n = 0; n < 16; n++) { h[n] = pws[n] * h[n] + du * Bl[n]; y += h[n] * Cl[n]; }
      y0s[t] = y;
    }
  } else {
    #pragma unroll
    for (int t = 0; t < 32; t++) {
      const float4* dq = (const float4*)(dtsS + (lb + t) * 12);
      float4 q0 = dq[0], q1 = dq[1], q2 = dq[2];
      float x = db + q0.x * w[0] + q0.y * w[1] + q0.z * w[2] + q0.w * w[3]
                   + q1.x * w[4] + q1.y * w[5] + q1.z * w[6] + q1.w * w[7]
                   + q2.x * w[8] + q2.y * w[9] + q2.z * w[10] + q2.w * w[11];
      float e = __expf(x);
      float delta = (x > 15.f) ? x : __logf(1.f + e);
      cum += delta; cumD[t] = cum;
      int p = dir_pix(k, s * 32 + t);
      float u = xc[(bpix + p) * 384 + d];
      float du = delta * u;
      const float4* Bq = (const float4*)(BsS + (lb + t) * 16);
      float4 b0 = Bq[0], b1 = Bq[1], b2 = Bq[2], b3 = Bq[3];
      float Bl[16] = {b0.x, b0.y, b0.z, b0.w, b1.x, b1.y, b1.z, b1.w,
                      b2.x, b2.y, b2.z, b2.w, b3.x, b3.y, b3.z, b3.w};
      const float4* Cq = (const float4*)(CsS + (lb + t) * 16);
      float4 c0 = Cq[0], c1 = Cq[1], c2 = Cq[2], c3 = Cq[3];
      float Cl[16] = {c0.x, c0.y, c0.z, c0.w, c1.x, c1.y, c1.z, c1.w,
                      c2.x, c2.y, c2.z, c2.w, c3.x, c3.y, c3.z, c3.w};
      float y = 0.f;
      #pragma unroll
      for (int n = 0; n < 16; n++) {
        float dA = __expf(delta * av[n]);
        h[n] = dA * h[n] + du * Bl[n];
        y += h[n] * Cl[n];
      }
      y0s[t] = y;
    }
  }

  // ---- phase B: publish + decoupled lookback ----
  float hin[16];
  long eb = ((long)g * 384 + d) * 16;
  if (s == 0) {
    #pragma unroll
    for (int n = 0; n < 16; n++) {
      __hip_atomic_store(&INCb[eb + n], h[n], __ATOMIC_RELAXED, __HIP_MEMORY_SCOPE_AGENT);
      hin[n] = 0.f;
    }
    __threadfence();
    __syncthreads();
    if (d == 0) __hip_atomic_store(&flags[g], 2, __ATOMIC_RELEASE, __HIP_MEMORY_SCOPE_AGENT);
  } else {
    #pragma unroll
    for (int n = 0; n < 16; n++)
      __hip_atomic_store(&Eb[eb + n], h[n], __ATOMIC_RELAXED, __HIP_MEMORY_SCOPE_AGENT);
    __hip_atomic_store(&Dend[(long)g * 384 + d], cum, __ATOMIC_RELAXED, __HIP_MEMORY_SCOPE_AGENT);
    __threadfence();
    __syncthreads();
    if (d == 0) __hip_atomic_store(&flags[g], 1, __ATOMIC_RELEASE, __HIP_MEMORY_SCOPE_AGENT);

    float Dacc = 0.f, Eacc[16];
    #pragma unroll
    for (int n = 0; n < 16; n++) Eacc[n] = 0.f;
    int j = s - 1;
    while (true) {
      __syncthreads();
      if (d == 0) {
        int f;
        do {
          f = __hip_atomic_load(&flags[chain * 128 + j], __ATOMIC_ACQUIRE, __HIP_MEMORY_SCOPE_AGENT);
        } while (f == 0);
        sh_f = f;
      }
      __syncthreads();
      int f = sh_f;
      long ej = ((long)(chain * 128 + j) * 384 + d) * 16;
      float pa[16];
      if (pw) { float ra = __expf(-Dacc); pow16(ra, pa); }
      else {
        #pragma unroll
        for (int n = 0; n < 16; n++) pa[n] = __expf(av[n] * Dacc);
      }
      if (f == 2) {
        #pragma unroll
        for (int n = 0; n < 16; n++) {
          float inc = __hip_atomic_load(&INCb[ej + n], __ATOMIC_RELAXED, __HIP_MEMORY_SCOPE_AGENT);
          hin[n] = pa[n] * inc + Eacc[n];
        }
        break;
      } else {
        #pragma unroll
        for (int n = 0; n < 16; n++) {
          float ev = __hip_atomic_load(&Eb[ej + n], __ATOMIC_RELAXED, __HIP_MEMORY_SCOPE_AGENT);
          Eacc[n] = pa[n] * ev + Eacc[n];
        }
        Dacc += __hip_atomic_load(&Dend[(long)(chain * 128 + j) * 384 + d], __ATOMIC_RELAXED, __HIP_MEMORY_SCOPE_AGENT);
        j--;
        if (j < 0) {
          #pragma unroll
          for (int n = 0; n < 16; n++) hin[n] = Eacc[n];
          break;
        }
      }
    }
    // publish own inclusive: INC = D_self * hin + E_self
    float ps[16];
    if (pw) { float rs = __expf(-cum); pow16(rs, ps); }
    else {
      #pragma unroll
      for (int n = 0; n < 16; n++) ps[n] = __expf(av[n] * cum);
    }
    #pragma unroll
    for (int n = 0; n < 16; n++)
      __hip_atomic_store(&INCb[eb + n], ps[n] * hin[n] + h[n], __ATOMIC_RELAXED, __HIP_MEMORY_SCOPE_AGENT);
    __threadfence();
    __syncthreads();
    if (d == 0) __hip_atomic_store(&flags[g], 2, __ATOMIC_RELEASE, __HIP_MEMORY_SCOPE_AGENT);
  }

  // ---- phase C: correction + output ----
  if (s == 0) {
    #pragma unroll
    for (int t = 0; t < 32; t++) {
      int p = dir_pix(k, s * 32 + t);
      atomicAdd(&ysum[(bpix + p) * 384 + d], y0s[t]);
    }
  } else if (pw) {
    #pragma unroll
    for (int t = 0; t < 32; t++) {
      const float4* Cq = (const float4*)(CsS + (lb + t) * 16);
      float4 c0 = Cq[0], c1 = Cq[1], c2 = Cq[2], c3 = Cq[3];
      float Cl[16] = {c0.x, c0.y, c0.z, c0.w, c1.x, c1.y, c1.z, c1.w,
                      c2.x, c2.y, c2.z, c2.w, c3.x, c3.y, c3.z, c3.w};
      float rc = __expf(-cumD[t]);
      float pc[16]; pow16(rc, pc);
      float corr = 0.f;
      #pragma unroll
      for (int n = 0; n < 16; n++) corr += Cl[n] * pc[n] * hin[n];
      int p = dir_pix(k, s * 32 + t);
      atomicAdd(&ysum[(bpix + p) * 384 + d], y0s[t] + corr);
    }
  } else {
    #pragma unroll
    for (int t = 0; t < 32; t++) {
      const float4* Cq = (const float4*)(CsS + (lb + t) * 16);
      float4 c0 = Cq[0], c1 = Cq[1], c2 = Cq[2], c3 = Cq[3];
      float Cl[16] = {c0.x, c0.y, c0.z, c0.w, c1.x, c1.y, c1.z, c1.w,
                      c2.x, c2.y, c2.z, c2.w, c3.x, c3.y, c3.z, c3.w};
      float corr = 0.f;
      #pragma unroll
      for (int n = 0; n < 16; n++) corr += Cl[n] * __expf(av[n] * cumD[t]) * hin[n];
      int p = dir_pix(k, s * 32 + t);
      atomicAdd(&ysum[(bpix + p) * 384 + d], y0s[t] + corr);
    }
  }
}

// ---------------- merge: ysum + D-skip + out-LN + silu(z) gate -> bf16 yact ----------------
__global__ __launch_bounds__(384) void k_merge(const float* __restrict__ ysum,
                                               const float* __restrict__ xc,
                                               const float* __restrict__ xz,
                                               const float* __restrict__ Ds,
                                               const float* __restrict__ g,
                                               const float* __restrict__ be,
                                               __hip_bfloat16* __restrict__ yactb) {
  int row = blockIdx.x;
  int d = threadIdx.x;
  float v = ysum[(long)row * 384 + d];
  float sd = Ds[d] + Ds[384 + d] + Ds[768 + d] + Ds[1152 + d];
  v += xc[(long)row * 384 + d] * sd;
  float s1 = v, s2 = v * v;
  #pragma unroll
  for (int o = 32; o > 0; o >>= 1) { s1 += __shfl_xor(s1, o); s2 += __shfl_xor(s2, o); }
  __shared__ float r1[6], r2[6];
  int wv = threadIdx.x >> 6;
  if ((threadIdx.x & 63) == 0) { r1[wv] = s1; r2[wv] = s2; }
  __syncthreads();
  float S1 = 0.f, S2 = 0.f;
  #pragma unroll
  for (int i = 0; i < 6; i++) { S1 += r1[i]; S2 += r2[i]; }
  float mu = S1 * (1.f / 384.f);
  float var = S2 * (1.f / 384.f) - mu * mu;
  float rr = rsqrtf(var + 1e-5f);
  float yn = (v - mu) * rr * g[d] + be[d];
  float z = xz[(long)row * 768 + 384 + d];
  float sg = z / (1.f + __expf(-z));
  yactb[(long)row * 384 + d] = __float2bfloat16(yn * sg);
}

extern "C" void kernel_launch(void* const* d_in, const int* in_sizes, int n_in,
                              void* d_out, int out_size, void* d_ws, size_t ws_size,
                              hipStream_t stream) {
  const float* input      = (const float*)d_in[0];
  const float* norm_g     = (const float*)d_in[1];
  const float* norm_b     = (const float*)d_in[2];
  const float* in_proj_w  = (const float*)d_in[3];
  const float* conv_w     = (const float*)d_in[4];
  const float* conv_b     = (const float*)d_in[5];
  const float* x_proj_w   = (const float*)d_in[6];
  const float* dt_w       = (const float*)d_in[7];
  const float* dt_b       = (const float*)d_in[8];
  const float* A_logs     = (const float*)d_in[9];
  const float* Ds         = (const float*)d_in[10];
  const float* out_norm_g = (const float*)d_in[11];
  const float* out_norm_b = (const float*)d_in[12];
  const float* out_proj_w = (const float*)d_in[13];
  float* out = (float*)d_out;

  float* ws = (float*)d_ws;
  __hip_bfloat16* xnb = (__hip_bfloat16*)ws;            //   786,432 f
  float* xz    = ws + 786432;                           // 6,291,456 f
  float* xc    = xz + 6291456;                          // 3,145,728 f
  __hip_bfloat16* xcb = (__hip_bfloat16*)(xc + 3145728);//  1,572,864 f
  __hip_bfloat16* Wt1 = (__hip_bfloat16*)(xc + 3145728 + 1572864);           // 73,728 f
  __hip_bfloat16* Wt2 = (__hip_bfloat16*)(xc + 3145728 + 1572864 + 73728);   // 36,864 f
  __hip_bfloat16* Wt3 = (__hip_bfloat16*)(xc + 3145728 + 1572864 + 110592);  // 36,864 f
  float* xdbl  = xc + 3145728 + 1572864 + 147456;       // 1,572,864 f
  float* dtsS  = xdbl + 1572864;                        //   393,216 f
  float* BsS   = dtsS + 393216;                         //   524,288 f
  float* CsS   = BsS + 524288;                          //   524,288 f
  float* Eb    = CsS + 524288;                          // 6,291,456 f (1024,384,16)
  float* INCb  = Eb + 6291456;                          // 6,291,456 f
  float* Dend  = INCb + 6291456;                        //   393,216 f (1024,384)
  int*   flags = (int*)(Dend + 393216);                 // 1024 ints + ticket
  int*   ticket = flags + 1024;
  float* ysum  = Dend + 393216 + 2048;                  // 3,145,728 f
  __hip_bfloat16* yactb = (__hip_bfloat16*)(ysum + 3145728);  // 1,572,864 f
  // total ≈ 32.7M floats ≈ 131 MB

  k_ln<<<dim3(2048), dim3(256), 0, stream>>>(input, norm_g, norm_b, xnb);
  k_packw<<<dim3(1152), dim3(256), 0, stream>>>(in_proj_w, x_proj_w, out_proj_w, Wt1, Wt2, Wt3);
  k_gemm_mfma<0><<<dim3(12, 64), dim3(256), 0, stream>>>(xnb, Wt1, nullptr, xz, 8192, 768, 192);
  k_conv<<<dim3(8192), dim3(384), 0, stream>>>(xz, conv_w, conv_b, xc, xcb);
  k_gemm_mfma<0><<<dim3(3, 64), dim3(256), 0, stream>>>(xcb, Wt2, nullptr, xdbl, 8192, 192, 384);
  k_repack<<<dim3(512), dim3(256), 0, stream>>>(xdbl, dtsS, BsS, CsS);
  hipMemsetAsync(flags, 0, 1025 * sizeof(int), stream);
  hipMemsetAsync(ysum, 0, 3145728 * sizeof(float), stream);
  k_scan_one<<<dim3(1024), dim3(384), 0, stream>>>(dtsS, BsS, CsS, xc, A_logs, dt_w, dt_b,
                                                   Eb, INCb, Dend, flags, ticket, ysum);
  k_merge<<<dim3(8192), dim3(384), 0, stream>>>(ysum, xc, xz, Ds, out_norm_g, out_norm_b, yactb);
  k_gemm_mfma<1><<<dim3(3, 64), dim3(256), 0, stream>>>(yactb, Wt3, input, out, 8192, 192, 384);
}

// Round 6
// 295.742 us; speedup vs baseline: 3.5772x; 3.5772x over previous
//
#include <hip/hip_runtime.h>
#include <hip/hip_bf16.h>

// VSSBlock: B=2 H=64 W=64 C=192 DM=384 N=16 R=12 K=4 L=4096
// R6: revert R5 lookback (1.6GB aggregate traffic, serialized tail). Back to R4's
//     pass0/combine/pass1, plus: (1) scalar cumDelta aggregate (P[16] never stored;
//     P=exp(av*cum) holds for BOTH power-trick and generic A), (2) sigmoid identity
//     + log-depth pow16 in the step loops, (3) x_proj GEMM epilogue scatters straight
//     into scan-ordered dts/Bs/Cs (k_repack deleted), (4) in_proj epilogue splits
//     x/z into separate stride-384 buffers (conv/merge fetch efficiency).

typedef __attribute__((ext_vector_type(8))) short short8;     // 8 bf16 = 4 VGPRs
typedef __attribute__((ext_vector_type(4))) float floatx4;    // fp32 accum frag

// ---------------- LayerNorm (pre-norm, eps 1e-6), C=192 -> bf16 ----------------
__global__ __launch_bounds__(256) void k_ln(const float* __restrict__ in,
                                            const float* __restrict__ g,
                                            const float* __restrict__ be,
                                            __hip_bfloat16* __restrict__ out) {
  int row = blockIdx.x * 4 + (threadIdx.x >> 6);
  int lane = threadIdx.x & 63;
  const float* x = in + (long)row * 192;
  float v0 = x[lane], v1 = x[lane + 64], v2 = x[lane + 128];
  float s = v0 + v1 + v2;
  float s2 = v0 * v0 + v1 * v1 + v2 * v2;
  #pragma unroll
  for (int o = 32; o > 0; o >>= 1) { s += __shfl_xor(s, o); s2 += __shfl_xor(s2, o); }
  float mu = s * (1.f / 192.f);
  float var = s2 * (1.f / 192.f) - mu * mu;
  float r = rsqrtf(var + 1e-6f);
  __hip_bfloat16* op = out + (long)row * 192;
  op[lane]       = __float2bfloat16((v0 - mu) * r * g[lane]       + be[lane]);
  op[lane + 64]  = __float2bfloat16((v1 - mu) * r * g[lane + 64]  + be[lane + 64]);
  op[lane + 128] = __float2bfloat16((v2 - mu) * r * g[lane + 128] + be[lane + 128]);
}

// ---------------- pack weights -> bf16, transposed to (N x K) ----------------
__global__ __launch_bounds__(256) void k_packw(const float* __restrict__ ipw,
                                               const float* __restrict__ xpw,
                                               const float* __restrict__ opw,
                                               __hip_bfloat16* __restrict__ Wt1,
                                               __hip_bfloat16* __restrict__ Wt2,
                                               __hip_bfloat16* __restrict__ Wt3) {
  int idx = blockIdx.x * 256 + threadIdx.x;
  if (idx < 147456) {                       // Wt1[n][k] = ipw[k][n]
    int n = idx / 192, k = idx - n * 192;
    Wt1[idx] = __float2bfloat16(ipw[(long)k * 768 + n]);
  } else if (idx < 147456 + 73728) {        // Wt2[j][d]
    int t = idx - 147456;
    int j = t / 384;
    float v = (j < 176) ? xpw[t] : 0.f;
    Wt2[t] = __float2bfloat16(v);
  } else if (idx < 147456 + 73728 + 73728) {// Wt3[n][k] = opw[k][n]
    int t = idx - 147456 - 73728;
    int n = t / 384, k = t - n * 384;
    Wt3[t] = __float2bfloat16(opw[(long)k * 192 + n]);
  }
}

// inverse direction map: pixel p -> scan position l for direction k (involutions)
__device__ __forceinline__ int inv_dir(int k, int p) {
  int pt = ((p & 63) << 6) | (p >> 6);
  if (k == 0) return p;
  if (k == 1) return pt;
  if (k == 2) return 4095 - p;
  return 4095 - pt;
}
// forward map (same involutions)
__device__ __forceinline__ int dir_pix(int k, int l) { return inv_dir(k, l); }

// ---------------- bf16 MFMA GEMM, 128x64 tile, BK=32; epilogue variants ----------------
// EPI 0: plain store to Co (MxN fp32)
// EPI 1: Co = acc + Res
// EPI 2: split: cols<384 -> Co (xbuf), cols>=384 -> Co2 (zbuf)  [N=768]
// EPI 3: scatter to scan-ordered dtsS/BsS/CsS; cols>=176 dropped [N=192]
template <int EPI>
__global__ __launch_bounds__(256) void k_gemm_mfma(const __hip_bfloat16* __restrict__ A,
                                                   const __hip_bfloat16* __restrict__ Bt,
                                                   const float* __restrict__ Res,
                                                   float* __restrict__ Co,
                                                   float* __restrict__ Co2,
                                                   float* __restrict__ dtsS,
                                                   float* __restrict__ BsS,
                                                   float* __restrict__ CsS,
                                                   int M, int N, int Kk) {
  __shared__ __align__(16) short As[128 * 32];
  __shared__ __align__(16) short Bs[64 * 32];
  int tid = threadIdx.x;
  int wave = tid >> 6, lane = tid & 63;
  int mlane = lane & 15, quad = lane >> 4;
  int row0 = blockIdx.y * 128, col0 = blockIdx.x * 64;
  int wr = wave & 1, wc = wave >> 1;
  floatx4 acc[4][2];
  #pragma unroll
  for (int mi = 0; mi < 4; mi++)
    #pragma unroll
    for (int ni = 0; ni < 2; ni++) acc[mi][ni] = (floatx4){0.f, 0.f, 0.f, 0.f};

  for (int k0 = 0; k0 < Kk; k0 += 32) {
    #pragma unroll
    for (int c = tid; c < 512; c += 256) {
      int r = c >> 2, off = (c & 3) * 8;
      *(float4*)&As[r * 32 + off] = *(const float4*)&A[(long)(row0 + r) * Kk + k0 + off];
    }
    {
      int c = tid;
      int r = c >> 2, off = (c & 3) * 8;
      *(float4*)&Bs[r * 32 + off] = *(const float4*)&Bt[(long)(col0 + r) * Kk + k0 + off];
    }
    __syncthreads();
    short8 af[4], bf[2];
    #pragma unroll
    for (int mi = 0; mi < 4; mi++)
      af[mi] = *(const short8*)&As[(wr * 64 + mi * 16 + mlane) * 32 + quad * 8];
    #pragma unroll
    for (int ni = 0; ni < 2; ni++)
      bf[ni] = *(const short8*)&Bs[(wc * 32 + ni * 16 + mlane) * 32 + quad * 8];
    #pragma unroll
    for (int mi = 0; mi < 4; mi++)
      #pragma unroll
      for (int ni = 0; ni < 2; ni++)
        acc[mi][ni] = __builtin_amdgcn_mfma_f32_16x16x32_bf16(af[mi], bf[ni], acc[mi][ni], 0, 0, 0);
    __syncthreads();
  }
  // C/D layout: col=lane&15, row=quad*4+reg  [m89-verified]
  #pragma unroll
  for (int mi = 0; mi < 4; mi++) {
    #pragma unroll
    for (int ni = 0; ni < 2; ni++) {
      int cc = col0 + wc * 32 + ni * 16 + mlane;
      #pragma unroll
      for (int i = 0; i < 4; i++) {
        int rr = row0 + wr * 64 + mi * 16 + quad * 4 + i;
        float v = acc[mi][ni][i];
        if (EPI == 0) {
          Co[(long)rr * N + cc] = v;
        } else if (EPI == 1) {
          Co[(long)rr * N + cc] = v + Res[(long)rr * N + cc];
        } else if (EPI == 2) {
          if (cc < 384) Co[(long)rr * 384 + cc] = v;
          else          Co2[(long)rr * 384 + (cc - 384)] = v;
        } else {  // EPI == 3: scatter into scan-ordered buffers
          if (cc < 176) {
            int k4 = (cc >= 132) ? 3 : (cc >= 88) ? 2 : (cc >= 44) ? 1 : 0;
            int c = cc - k4 * 44;
            int b = rr >> 12, p = rr & 4095;
            int l = inv_dir(k4, p);
            long lbase = ((long)((b << 2) + k4) << 12) + l;
            if (c < 12)      dtsS[lbase * 12 + c] = v;
            else if (c < 28) BsS[lbase * 16 + (c - 12)] = v;
            else             CsS[lbase * 16 + (c - 28)] = v;
          }
        }
      }
    }
  }
}

// ---------------- depthwise 3x3 conv + bias + SiLU; reads xbuf (stride 384) ----------------
__global__ __launch_bounds__(384) void k_conv(const float* __restrict__ xbuf,
                                              const float* __restrict__ cw,
                                              const float* __restrict__ cb,
                                              float* __restrict__ xc,
                                              __hip_bfloat16* __restrict__ xcb) {
  int row = blockIdx.x;
  int b = row >> 12, p = row & 4095;
  int h = p >> 6, w0 = p & 63;
  int d = threadIdx.x;
  float acc = cb[d];
  const float* wt = cw + d * 9;
  #pragma unroll
  for (int dh = -1; dh <= 1; dh++) {
    int hh = h + dh;
    if (hh < 0 || hh > 63) continue;
    #pragma unroll
    for (int dw = -1; dw <= 1; dw++) {
      int ww = w0 + dw;
      if (ww < 0 || ww > 63) continue;
      acc += xbuf[((long)(b << 12) + (hh << 6) + ww) * 384 + d] * wt[(dh + 1) * 3 + (dw + 1)];
    }
  }
  float sg = 1.f / (1.f + __expf(-acc));
  float v = acc * sg;
  xc[(long)row * 384 + d] = v;
  xcb[(long)row * 384 + d] = __float2bfloat16(v);
}

// powers: pws[n] = r^(n+1), log-depth pairing
__device__ __forceinline__ void pow16(float r, float* pws) {
  pws[0] = r;
  #pragma unroll
  for (int n = 1; n < 16; n++) {
    int m = n + 1, c = (m + 1) / 2, f = m - c;
    pws[n] = pws[c - 1] * pws[f - 1];
  }
}

// ---------------- scan pass 0: per-segment endpoint E[16] + scalar cumDelta ----------------
// block = (bk, s): 128 segments x 32 steps; thread = channel d.
__global__ __launch_bounds__(384) void k_scan0(
    const float* __restrict__ dtsS, const float* __restrict__ BsS,
    const float* __restrict__ xc,
    const float* __restrict__ A_logs, const float* __restrict__ dt_w,
    const float* __restrict__ dt_b,
    float* __restrict__ Eb, float* __restrict__ Dend) {
  int bid = blockIdx.x;
  int s = bid & 127, bk = bid >> 7;
  int k = bk & 3, b = bk >> 2;
  int d = threadIdx.x;
  float w[12];
  const float* dwp = dt_w + ((long)(k * 384) + d) * 12;
  #pragma unroll
  for (int r = 0; r < 12; r++) w[r] = dwp[r];
  float db = dt_b[k * 384 + d];
  const float* al = A_logs + ((long)(k * 384) + d) * 16;
  bool pw = true;
  float av[16];
  #pragma unroll
  for (int n = 0; n < 16; n++) {
    float a = __expf(al[n]);
    av[n] = -a;
    pw = pw && (fabsf(a - (float)(n + 1)) < 1e-3f);
  }
  float h[16];
  #pragma unroll
  for (int n = 0; n < 16; n++) h[n] = 0.f;
  float cum = 0.f;
  long lb = (long)bk * 4096 + s * 32;
  long bpix = (long)(b << 12);

  if (pw) {
    #pragma unroll 4
    for (int t = 0; t < 32; t++) {
      const float4* dq = (const float4*)(dtsS + (lb + t) * 12);
      float4 q0 = dq[0], q1 = dq[1], q2 = dq[2];
      float x = db + q0.x * w[0] + q0.y * w[1] + q0.z * w[2] + q0.w * w[3]
                   + q1.x * w[4] + q1.y * w[5] + q1.z * w[6] + q1.w * w[7]
                   + q2.x * w[8] + q2.y * w[9] + q2.z * w[10] + q2.w * w[11];
      float e = __expf(x);
      float delta = (x > 15.f) ? x : __logf(1.f + e);
      cum += delta;
      int p = dir_pix(k, s * 32 + t);
      float u = xc[(bpix + p) * 384 + d];
      float du = delta * u;
      float rr = __builtin_amdgcn_rcpf(1.f + e);  // exp(-softplus(x))
      float pws[16]; pow16(rr, pws);
      const float4* Bq = (const float4*)(BsS + (lb + t) * 16);
      float4 b0 = Bq[0], b1 = Bq[1], b2 = Bq[2], b3 = Bq[3];
      float Bl[16] = {b0.x, b0.y, b0.z, b0.w, b1.x, b1.y, b1.z, b1.w,
                      b2.x, b2.y, b2.z, b2.w, b3.x, b3.y, b3.z, b3.w};
      #pragma unroll
      for (int n = 0; n < 16; n++) h[n] = pws[n] * h[n] + du * Bl[n];
    }
  } else {
    for (int t = 0; t < 32; t++) {
      const float4* dq = (const float4*)(dtsS + (lb + t) * 12);
      float4 q0 = dq[0], q1 = dq[1], q2 = dq[2];
      float x = db + q0.x * w[0] + q0.y * w[1] + q0.z * w[2] + q0.w * w[3]
                   + q1.x * w[4] + q1.y * w[5] + q1.z * w[6] + q1.w * w[7]
                   + q2.x * w[8] + q2.y * w[9] + q2.z * w[10] + q2.w * w[11];
      float e = __expf(x);
      float delta = (x > 15.f) ? x : __logf(1.f + e);
      cum += delta;
      int p = dir_pix(k, s * 32 + t);
      float u = xc[(bpix + p) * 384 + d];
      float du = delta * u;
      const float4* Bq = (const float4*)(BsS + (lb + t) * 16);
      float4 b0 = Bq[0], b1 = Bq[1], b2 = Bq[2], b3 = Bq[3];
      float Bl[16] = {b0.x, b0.y, b0.z, b0.w, b1.x, b1.y, b1.z, b1.w,
                      b2.x, b2.y, b2.z, b2.w, b3.x, b3.y, b3.z, b3.w};
      #pragma unroll
      for (int n = 0; n < 16; n++) {
        float dA = __expf(delta * av[n]);
        h[n] = dA * h[n] + du * Bl[n];
      }
    }
  }
  int g = bk * 128 + s;
  float* Ep = Eb + ((long)g * 384 + d) * 16;
  #pragma unroll
  for (int n = 0; n < 16; n++) Ep[n] = h[n];
  Dend[(long)g * 384 + d] = cum;
}

// ---------------- cross-segment combine: P = exp(av*cum) (works for both paths) ----------------
__global__ __launch_bounds__(256) void k_combine(const float* __restrict__ Eb,
                                                 const float* __restrict__ Dend,
                                                 const float* __restrict__ A_logs,
                                                 float* __restrict__ Hin) {
  int t = blockIdx.x * 256 + threadIdx.x;  // B*K*6144 = 49152
  int bk = t / 6144;
  int dn = t - bk * 6144;
  int k = bk & 3;
  int d = dn >> 4;
  float av = -__expf(A_logs[(long)k * 6144 + dn]);
  float h = 0.f;
  long ebase = (long)bk * 128 * 6144 + dn;
  long dbase = (long)bk * 128 * 384 + d;
  for (int s = 0; s < 128; s++) {
    Hin[ebase + (long)s * 6144] = h;
    float cum = Dend[dbase + (long)s * 384];
    h = __expf(av * cum) * h + Eb[ebase + (long)s * 6144];
  }
}

// ---------------- scan pass 1: full recurrence from Hin, atomicAdd y into ysum ----------------
__global__ __launch_bounds__(384) void k_scan1(
    const float* __restrict__ dtsS, const float* __restrict__ BsS,
    const float* __restrict__ CsS, const float* __restrict__ xc,
    const float* __restrict__ A_logs, const float* __restrict__ dt_w,
    const float* __restrict__ dt_b, const float* __restrict__ Hin,
    float* __restrict__ ysum) {
  int bid = blockIdx.x;
  int s = bid & 127, bk = bid >> 7;
  int k = bk & 3, b = bk >> 2;
  int d = threadIdx.x;
  float w[12];
  const float* dwp = dt_w + ((long)(k * 384) + d) * 12;
  #pragma unroll
  for (int r = 0; r < 12; r++) w[r] = dwp[r];
  float db = dt_b[k * 384 + d];
  const float* al = A_logs + ((long)(k * 384) + d) * 16;
  bool pw = true;
  float av[16];
  #pragma unroll
  for (int n = 0; n < 16; n++) {
    float a = __expf(al[n]);
    av[n] = -a;
    pw = pw && (fabsf(a - (float)(n + 1)) < 1e-3f);
  }
  float h[16];
  const float* hp = Hin + ((long)bk * 128 + s) * 6144 + d * 16;
  #pragma unroll
  for (int n = 0; n < 16; n++) h[n] = hp[n];
  long lb = (long)bk * 4096 + s * 32;
  long bpix = (long)(b << 12);

  if (pw) {
    #pragma unroll 4
    for (int t = 0; t < 32; t++) {
      const float4* dq = (const float4*)(dtsS + (lb + t) * 12);
      float4 q0 = dq[0], q1 = dq[1], q2 = dq[2];
      float x = db + q0.x * w[0] + q0.y * w[1] + q0.z * w[2] + q0.w * w[3]
                   + q1.x * w[4] + q1.y * w[5] + q1.z * w[6] + q1.w * w[7]
                   + q2.x * w[8] + q2.y * w[9] + q2.z * w[10] + q2.w * w[11];
      float e = __expf(x);
      float delta = (x > 15.f) ? x : __logf(1.f + e);
      int p = dir_pix(k, s * 32 + t);
      float u = xc[(bpix + p) * 384 + d];
      float du = delta * u;
      float rr = __builtin_amdgcn_rcpf(1.f + e);
      float pws[16]; pow16(rr, pws);
      const float4* Bq = (const float4*)(BsS + (lb + t) * 16);
      float4 b0 = Bq[0], b1 = Bq[1], b2 = Bq[2], b3 = Bq[3];
      float Bl[16] = {b0.x, b0.y, b0.z, b0.w, b1.x, b1.y, b1.z, b1.w,
                      b2.x, b2.y, b2.z, b2.w, b3.x, b3.y, b3.z, b3.w};
      const float4* Cq = (const float4*)(CsS + (lb + t) * 16);
      float4 c0 = Cq[0], c1 = Cq[1], c2 = Cq[2], c3 = Cq[3];
      float Cl[16] = {c0.x, c0.y, c0.z, c0.w, c1.x, c1.y, c1.z, c1.w,
                      c2.x, c2.y, c2.z, c2.w, c3.x, c3.y, c3.z, c3.w};
      float y = 0.f;
      #pragma unroll
      for (int n = 0; n < 16; n++) { h[n] = pws[n] * h[n] + du * Bl[n]; y += h[n] * Cl[n]; }
      atomicAdd(&ysum[(bpix + p) * 384 + d], y);
    }
  } else {
    for (int t = 0; t < 32; t++) {
      const float4* dq = (const float4*)(dtsS + (lb + t) * 12);
      float4 q0 = dq[0], q1 = dq[1], q2 = dq[2];
      float x = db + q0.x * w[0] + q0.y * w[1] + q0.z * w[2] + q0.w * w[3]
                   + q1.x * w[4] + q1.y * w[5] + q1.z * w[6] + q1.w * w[7]
                   + q2.x * w[8] + q2.y * w[9] + q2.z * w[10] + q2.w * w[11];
      float e = __expf(x);
      float delta = (x > 15.f) ? x : __logf(1.f + e);
      int p = dir_pix(k, s * 32 + t);
      float u = xc[(bpix + p) * 384 + d];
      float du = delta * u;
      const float4* Bq = (const float4*)(BsS + (lb + t) * 16);
      float4 b0 = Bq[0], b1 = Bq[1], b2 = Bq[2], b3 = Bq[3];
      float Bl[16] = {b0.x, b0.y, b0.z, b0.w, b1.x, b1.y, b1.z, b1.w,
                      b2.x, b2.y, b2.z, b2.w, b3.x, b3.y, b3.z, b3.w};
      const float4* Cq = (const float4*)(CsS + (lb + t) * 16);
      float4 c0 = Cq[0], c1 = Cq[1], c2 = Cq[2], c3 = Cq[3];
      float Cl[16] = {c0.x, c0.y, c0.z, c0.w, c1.x, c1.y, c1.z, c1.w,
                      c2.x, c2.y, c2.z, c2.w, c3.x, c3.y, c3.z, c3.w};
      float y = 0.f;
      #pragma unroll
      for (int n = 0; n < 16; n++) {
        float dA = __expf(delta * av[n]);
        h[n] = dA * h[n] + du * Bl[n];
        y += h[n] * Cl[n];
      }
      atomicAdd(&ysum[(bpix + p) * 384 + d], y);
    }
  }
}

// ---------------- merge: ysum + D-skip + out-LN + silu(z) gate -> bf16 yact ----------------
__global__ __launch_bounds__(384) void k_merge(const float* __restrict__ ysum,
                                               const float* __restrict__ xc,
                                               const float* __restrict__ zbuf,
                                               const float* __restrict__ Ds,
                                               const float* __restrict__ g,
                                               const float* __restrict__ be,
                                               __hip_bfloat16* __restrict__ yactb) {
  int row = blockIdx.x;
  int d = threadIdx.x;
  float v = ysum[(long)row * 384 + d];
  float sd = Ds[d] + Ds[384 + d] + Ds[768 + d] + Ds[1152 + d];
  v += xc[(long)row * 384 + d] * sd;
  float s1 = v, s2 = v * v;
  #pragma unroll
  for (int o = 32; o > 0; o >>= 1) { s1 += __shfl_xor(s1, o); s2 += __shfl_xor(s2, o); }
  __shared__ float r1[6], r2[6];
  int wv = threadIdx.x >> 6;
  if ((threadIdx.x & 63) == 0) { r1[wv] = s1; r2[wv] = s2; }
  __syncthreads();
  float S1 = 0.f, S2 = 0.f;
  #pragma unroll
  for (int i = 0; i < 6; i++) { S1 += r1[i]; S2 += r2[i]; }
  float mu = S1 * (1.f / 384.f);
  float var = S2 * (1.f / 384.f) - mu * mu;
  float rr = rsqrtf(var + 1e-5f);
  float yn = (v - mu) * rr * g[d] + be[d];
  float z = zbuf[(long)row * 384 + d];
  float sg = z / (1.f + __expf(-z));
  yactb[(long)row * 384 + d] = __float2bfloat16(yn * sg);
}

extern "C" void kernel_launch(void* const* d_in, const int* in_sizes, int n_in,
                              void* d_out, int out_size, void* d_ws, size_t ws_size,
                              hipStream_t stream) {
  const float* input      = (const float*)d_in[0];
  const float* norm_g     = (const float*)d_in[1];
  const float* norm_b     = (const float*)d_in[2];
  const float* in_proj_w  = (const float*)d_in[3];
  const float* conv_w     = (const float*)d_in[4];
  const float* conv_b     = (const float*)d_in[5];
  const float* x_proj_w   = (const float*)d_in[6];
  const float* dt_w       = (const float*)d_in[7];
  const float* dt_b       = (const float*)d_in[8];
  const float* A_logs     = (const float*)d_in[9];
  const float* Ds         = (const float*)d_in[10];
  const float* out_norm_g = (const float*)d_in[11];
  const float* out_norm_b = (const float*)d_in[12];
  const float* out_proj_w = (const float*)d_in[13];
  float* out = (float*)d_out;

  float* ws = (float*)d_ws;
  __hip_bfloat16* xnb = (__hip_bfloat16*)ws;              //   393,216 f (8192x192 bf16)
  float* xbuf  = ws + 393216;                             // 3,145,728 f (B,L,384)
  float* zbuf  = xbuf + 3145728;                          // 3,145,728 f
  float* xc    = zbuf + 3145728;                          // 3,145,728 f
  __hip_bfloat16* xcb = (__hip_bfloat16*)(xc + 3145728);  // 1,572,864 f (8192x384 bf16)
  __hip_bfloat16* Wt1 = (__hip_bfloat16*)(xc + 3145728 + 1572864);           // 73,728 f
  __hip_bfloat16* Wt2 = (__hip_bfloat16*)(xc + 3145728 + 1572864 + 73728);   // 36,864 f
  __hip_bfloat16* Wt3 = (__hip_bfloat16*)(xc + 3145728 + 1572864 + 110592);  // 36,864 f
  float* dtsS  = xc + 3145728 + 1572864 + 147456;         //   393,216 f (BK,L,12)
  float* BsS   = dtsS + 393216;                           //   524,288 f
  float* CsS   = BsS + 524288;                            //   524,288 f
  float* Eb    = CsS + 524288;                            // 6,291,456 f (1024,6144)
  float* Dend  = Eb + 6291456;                            //   393,216 f (1024,384)
  float* Hb    = Dend + 393216;                           // 6,291,456 f
  float* ysum  = Hb + 6291456;                            // 3,145,728 f
  __hip_bfloat16* yactb = (__hip_bfloat16*)(ysum + 3145728);  // 1,572,864 f
  // total ≈ 30.9M floats ≈ 124 MB

  k_ln<<<dim3(2048), dim3(256), 0, stream>>>(input, norm_g, norm_b, xnb);
  k_packw<<<dim3(1152), dim3(256), 0, stream>>>(in_proj_w, x_proj_w, out_proj_w, Wt1, Wt2, Wt3);
  // in_proj: (8192x192)@(192x768), split epilogue -> xbuf/zbuf
  k_gemm_mfma<2><<<dim3(12, 64), dim3(256), 0, stream>>>(xnb, Wt1, nullptr, xbuf, zbuf,
                                                         nullptr, nullptr, nullptr, 8192, 768, 192);
  k_conv<<<dim3(8192), dim3(384), 0, stream>>>(xbuf, conv_w, conv_b, xc, xcb);
  // x_proj: (8192x384)@(384x192), scatter epilogue -> dtsS/BsS/CsS (scan order)
  k_gemm_mfma<3><<<dim3(3, 64), dim3(256), 0, stream>>>(xcb, Wt2, nullptr, nullptr, nullptr,
                                                        dtsS, BsS, CsS, 8192, 192, 384);
  k_scan0<<<dim3(1024), dim3(384), 0, stream>>>(dtsS, BsS, xc, A_logs, dt_w, dt_b, Eb, Dend);
  k_combine<<<dim3(192), dim3(256), 0, stream>>>(Eb, Dend, A_logs, Hb);
  hipMemsetAsync(ysum, 0, 3145728 * sizeof(float), stream);
  k_scan1<<<dim3(1024), dim3(384), 0, stream>>>(dtsS, BsS, CsS, xc, A_logs, dt_w, dt_b, Hb, ysum);
  k_merge<<<dim3(8192), dim3(384), 0, stream>>>(ysum, xc, zbuf, Ds, out_norm_g, out_norm_b, yactb);
  // out_proj + residual: (8192x384)@(384x192) + input
  k_gemm_mfma<1><<<dim3(3, 64), dim3(256), 0, stream>>>(yactb, Wt3, input, out, nullptr,
                                                        nullptr, nullptr, nullptr, 8192, 192, 384);
}